// Round 7
// baseline (134.481 us; speedup 1.0000x reference)
//
#include <hip/hip_runtime.h>

constexpr int K  = 3;
constexpr int Hc = 512, Wc = 512, Bc = 8;
constexpr int HWc = Hc * Wc;

typedef __attribute__((ext_vector_type(2))) unsigned int u32x2;
typedef __attribute__((ext_vector_type(4))) unsigned int u32x4;

__device__ __forceinline__ float bl32(__amdgpu_buffer_rsrc_t r, int vo, int so) {
    return __uint_as_float(__builtin_amdgcn_raw_buffer_load_b32(r, vo, so, 0));
}
__device__ __forceinline__ u32x2 bl64(__amdgpu_buffer_rsrc_t r, int vo, int so) {
    return __builtin_amdgcn_raw_buffer_load_b64(r, vo, so, 0);
}
__device__ __forceinline__ u32x4 bl128(__amdgpu_buffer_rsrc_t r, int vo, int so) {
    return __builtin_amdgcn_raw_buffer_load_b128(r, vo, so, 0);
}
__device__ __forceinline__ unsigned umax2(unsigned a, unsigned b) { return a > b ? a : b; }

__global__ __launch_bounds__(256, 8) void deform_conv2d_kernel(
    const float* __restrict__ inp,     // (B,H,W)
    const float* __restrict__ wgt,     // (K*K)
    const float* __restrict__ off,     // (B, 2*K*K, H, W)
    float* __restrict__ out)           // (B,H,W)
{
    const int idx = blockIdx.x * blockDim.x + threadIdx.x;   // 4 pixels per thread
    const int p4  = idx << 2;
    const int b   = p4 >> 18;            // / (512*512)
    const int hw  = p4 & (HWc - 1);
    const int h   = hw >> 9;
    const int w   = hw & (Wc - 1);       // multiple of 4

    __amdgpu_buffer_rsrc_t orsrc = __builtin_amdgcn_make_buffer_rsrc(
        (void*)(off + (size_t)b * (2 * K * K) * HWc), (short)0,
        (2 * K * K) * HWc * 4, 0x00020000);
    __amdgpu_buffer_rsrc_t irsrc = __builtin_amdgcn_make_buffer_rsrc(
        (void*)(inp + (size_t)b * HWc), (short)0, HWc * 4, 0x00020000);

    float wk[K * K];
#pragma unroll
    for (int k = 0; k < K * K; ++k) wk[k] = wgt[k];   // wave-uniform s_loads

    // ---- shared 4x7 window: rows h-1..h+2, cols w-1..w+5 (zero-padded) ----
    // Row OOB handled free by SRD bounds check (flat index wraps OOB -> 0).
    // Column wrap-aliasing fixed by 3 masks.
    const int  fbB = ((h - 1) * Wc + (w - 1)) * 4;
    const bool m0 = (w >= 1);
    const bool m5 = (w + 4 < Wc);
    const bool m6 = (w + 5 < Wc);

    float win[4][7];
#pragma unroll
    for (int r = 0; r < 4; ++r) {
        const int rb = fbB + r * Wc * 4;
        const float e0 = bl32 (irsrc, rb,      0);   // col w-1
        const u32x4 md = bl128(irsrc, rb + 4,  0);   // cols w..w+3 (16B aligned)
        const u32x2 e5 = bl64 (irsrc, rb + 20, 0);   // cols w+4,w+5 (8B aligned)
        win[r][0] = m0 ? e0 : 0.f;
        win[r][1] = __uint_as_float(md.x);
        win[r][2] = __uint_as_float(md.y);
        win[r][3] = __uint_as_float(md.z);
        win[r][4] = __uint_as_float(md.w);
        win[r][5] = m5 ? __uint_as_float(e5.x) : 0.f;
        win[r][6] = m6 ? __uint_as_float(e5.y) : 0.f;
    }

    const int hwB = hw * 4;
    float acc[4] = {0.f, 0.f, 0.f, 0.f};

    // Fast path runs UNCONDITIONALLY; validity (all 72 offset values in [0,1))
    // is checked once at the end via bit pattern: f in [0,1) <=> bits < 0x3F800000u
    // (negatives/NaN/Inf/>=1 all have larger unsigned bit patterns).
    unsigned vmax = 0u;

#pragma unroll
    for (int k = 0; k < K * K; ++k) {
        const int ky = k / K - 1;
        const int kx = k % K - 1;

        const u32x4 oyu = bl128(orsrc, hwB, (2 * k)     * HWc * 4);
        const u32x4 oxu = bl128(orsrc, hwB, (2 * k + 1) * HWc * 4);

        vmax = umax2(vmax, umax2(umax2(umax2(oyu.x, oyu.y), umax2(oyu.z, oyu.w)),
                                 umax2(umax2(oxu.x, oxu.y), umax2(oxu.z, oxu.w))));

        const int r0 = ky + 1;
#pragma unroll
        for (int j = 0; j < 4; ++j) {
            const int   c  = j + kx + 1;                 // static after unroll
            const float oy = __uint_as_float(j == 0 ? oyu.x : j == 1 ? oyu.y : j == 2 ? oyu.z : oyu.w);
            const float ox = __uint_as_float(j == 0 ? oxu.x : j == 1 ? oxu.y : j == 2 ? oxu.z : oxu.w);
            const float t  = win[r0][c]     + ox * (win[r0][c + 1]     - win[r0][c]);
            const float bo = win[r0 + 1][c] + ox * (win[r0 + 1][c + 1] - win[r0 + 1][c]);
            acc[j] += wk[k] * (t + oy * (bo - t));
        }
    }

    if (!__all(vmax < 0x3F800000u)) {
        // GENERAL PATH (wave-uniform, never taken for this data): recompute from
        // scratch with arbitrary-offset bilinear. Runtime loop (#pragma unroll 1)
        // blocks CSE with the fast path's loads, keeping VGPR pressure low.
        acc[0] = acc[1] = acc[2] = acc[3] = 0.f;
#pragma unroll 1
        for (int k = 0; k < K * K; ++k) {
            const int ky = k / K - 1;
            const int kx = k % K - 1;

            const u32x4 oyu = bl128(orsrc, hwB, (2 * k)     * HWc * 4);
            const u32x4 oxu = bl128(orsrc, hwB, (2 * k + 1) * HWc * 4);
            const float oya[4] = {__uint_as_float(oyu.x), __uint_as_float(oyu.y),
                                  __uint_as_float(oyu.z), __uint_as_float(oyu.w)};
            const float oxa[4] = {__uint_as_float(oxu.x), __uint_as_float(oxu.y),
                                  __uint_as_float(oxu.z), __uint_as_float(oxu.w)};

#pragma unroll
            for (int j = 0; j < 4; ++j) {
                const float y = (float)(h + ky)     + oya[j];
                const float x = (float)(w + j + kx) + oxa[j];
                const float y0f = floorf(y), x0f = floorf(x);
                const float ly = y - y0f,  lx = x - x0f;
                const int y0 = (int)y0f, x0 = (int)x0f;

                const int cb = ((y0 << 9) + x0) * 4;
                float v00 = bl32(irsrc, cb,              0);
                float v01 = bl32(irsrc, cb + 4,          0);
                float v10 = bl32(irsrc, cb + Wc * 4,     0);
                float v11 = bl32(irsrc, cb + Wc * 4 + 4, 0);
                const bool vx0 = (unsigned)x0       < (unsigned)Wc;
                const bool vx1 = (unsigned)(x0 + 1) < (unsigned)Wc;
                v00 = vx0 ? v00 : 0.f;   v10 = vx0 ? v10 : 0.f;
                v01 = vx1 ? v01 : 0.f;   v11 = vx1 ? v11 : 0.f;

                const float top = v00 + lx * (v01 - v00);
                const float bot = v10 + lx * (v11 - v10);
                acc[j] += wk[k] * (top + ly * (bot - top));
            }
        }
    }

    float4 o;
    o.x = acc[0]; o.y = acc[1]; o.z = acc[2]; o.w = acc[3];
    *reinterpret_cast<float4*>(out + p4) = o;    // 16B aligned, coalesced
}

extern "C" void kernel_launch(void* const* d_in, const int* in_sizes, int n_in,
                              void* d_out, int out_size, void* d_ws, size_t ws_size,
                              hipStream_t stream)
{
    const float* inp = (const float*)d_in[0];   // (8,512,512)
    const float* wgt = (const float*)d_in[1];   // (1,1,3,3) = 9 floats
    const float* off = (const float*)d_in[2];   // (8,18,512,512)
    float* out = (float*)d_out;

    const int nthreads = Bc * HWc / 4;          // 4 px per thread
    const int block = 256;
    const int grid  = nthreads / block;         // 2048

    deform_conv2d_kernel<<<grid, block, 0, stream>>>(inp, wgt, off, out);
}

// Round 8
// 117.960 us; speedup vs baseline: 1.1401x; 1.1401x over previous
//
#include <hip/hip_runtime.h>

constexpr int K  = 3;
constexpr int Hc = 512, Wc = 512, Bc = 8;
constexpr int HWc = Hc * Wc;

typedef __attribute__((ext_vector_type(2))) unsigned int u32x2;
typedef __attribute__((ext_vector_type(4))) unsigned int u32x4;

__device__ __forceinline__ float bl32(__amdgpu_buffer_rsrc_t r, int vo, int so) {
    return __uint_as_float(__builtin_amdgcn_raw_buffer_load_b32(r, vo, so, 0));
}
__device__ __forceinline__ u32x2 bl64(__amdgpu_buffer_rsrc_t r, int vo, int so) {
    return __builtin_amdgcn_raw_buffer_load_b64(r, vo, so, 0);
}
__device__ __forceinline__ u32x4 bl128(__amdgpu_buffer_rsrc_t r, int vo, int so) {
    return __builtin_amdgcn_raw_buffer_load_b128(r, vo, so, 0);
}
__device__ __forceinline__ unsigned umax2(unsigned a, unsigned b) { return a > b ? a : b; }

__global__ __launch_bounds__(256, 6) void deform_conv2d_kernel(
    const float* __restrict__ inp,     // (B,H,W)
    const float* __restrict__ wgt,     // (K*K)
    const float* __restrict__ off,     // (B, 2*K*K, H, W)
    float* __restrict__ out)           // (B,H,W)
{
    const int idx = blockIdx.x * blockDim.x + threadIdx.x;   // 4 pixels per thread
    const int p4  = idx << 2;
    const int b   = p4 >> 18;            // / (512*512)
    const int hw  = p4 & (HWc - 1);
    const int h   = hw >> 9;
    const int w   = hw & (Wc - 1);       // multiple of 4

    __amdgpu_buffer_rsrc_t orsrc = __builtin_amdgcn_make_buffer_rsrc(
        (void*)(off + (size_t)b * (2 * K * K) * HWc), (short)0,
        (2 * K * K) * HWc * 4, 0x00020000);
    __amdgpu_buffer_rsrc_t irsrc = __builtin_amdgcn_make_buffer_rsrc(
        (void*)(inp + (size_t)b * HWc), (short)0, HWc * 4, 0x00020000);

    float wk[K * K];
#pragma unroll
    for (int k = 0; k < K * K; ++k) wk[k] = wgt[k];   // wave-uniform s_loads

    // ---- shared 4x7 window: rows h-1..h+2, cols w-1..w+5 (zero-padded) ----
    // Row OOB handled free by SRD bounds check (flat index wraps OOB -> 0).
    // Column wrap-aliasing fixed by 3 masks.
    const int  fbB = ((h - 1) * Wc + (w - 1)) * 4;
    const bool m0 = (w >= 1);
    const bool m5 = (w + 4 < Wc);
    const bool m6 = (w + 5 < Wc);

    float win[4][7];
#pragma unroll
    for (int r = 0; r < 4; ++r) {
        const int rb = fbB + r * Wc * 4;
        const float e0 = bl32 (irsrc, rb,      0);   // col w-1
        const u32x4 md = bl128(irsrc, rb + 4,  0);   // cols w..w+3 (16B aligned)
        const u32x2 e5 = bl64 (irsrc, rb + 20, 0);   // cols w+4,w+5 (8B aligned)
        win[r][0] = m0 ? e0 : 0.f;
        win[r][1] = __uint_as_float(md.x);
        win[r][2] = __uint_as_float(md.y);
        win[r][3] = __uint_as_float(md.z);
        win[r][4] = __uint_as_float(md.w);
        win[r][5] = m5 ? __uint_as_float(e5.x) : 0.f;
        win[r][6] = m6 ? __uint_as_float(e5.y) : 0.f;
    }

    const int hwB = hw * 4;
    float acc[4] = {0.f, 0.f, 0.f, 0.f};

    // Fast path runs UNCONDITIONALLY; validity (all 72 offset values in [0,1))
    // is checked once at the end via bit pattern: f in [0,1) <=> bits < 0x3F800000u
    // (negatives/NaN/Inf/>=1 all have larger unsigned bit patterns).
    unsigned vmax = 0u;

#pragma unroll
    for (int k = 0; k < K * K; ++k) {
        const int ky = k / K - 1;
        const int kx = k % K - 1;

        const u32x4 oyu = bl128(orsrc, hwB, (2 * k)     * HWc * 4);
        const u32x4 oxu = bl128(orsrc, hwB, (2 * k + 1) * HWc * 4);

        vmax = umax2(vmax, umax2(umax2(umax2(oyu.x, oyu.y), umax2(oyu.z, oyu.w)),
                                 umax2(umax2(oxu.x, oxu.y), umax2(oxu.z, oxu.w))));

        const int r0 = ky + 1;
#pragma unroll
        for (int j = 0; j < 4; ++j) {
            const int   c  = j + kx + 1;                 // static after unroll
            const float oy = __uint_as_float(j == 0 ? oyu.x : j == 1 ? oyu.y : j == 2 ? oyu.z : oyu.w);
            const float ox = __uint_as_float(j == 0 ? oxu.x : j == 1 ? oxu.y : j == 2 ? oxu.z : oxu.w);
            const float t  = win[r0][c]     + ox * (win[r0][c + 1]     - win[r0][c]);
            const float bo = win[r0 + 1][c] + ox * (win[r0 + 1][c + 1] - win[r0 + 1][c]);
            acc[j] += wk[k] * (t + oy * (bo - t));
        }
    }

    if (!__all(vmax < 0x3F800000u)) {
        // GENERAL PATH (wave-uniform, never taken for this data): recompute from
        // scratch with arbitrary-offset bilinear. Runtime loop (#pragma unroll 1)
        // blocks CSE with the fast path's loads, keeping VGPR pressure low.
        acc[0] = acc[1] = acc[2] = acc[3] = 0.f;
#pragma unroll 1
        for (int k = 0; k < K * K; ++k) {
            const int ky = k / K - 1;
            const int kx = k % K - 1;

            const u32x4 oyu = bl128(orsrc, hwB, (2 * k)     * HWc * 4);
            const u32x4 oxu = bl128(orsrc, hwB, (2 * k + 1) * HWc * 4);
            const float oya[4] = {__uint_as_float(oyu.x), __uint_as_float(oyu.y),
                                  __uint_as_float(oyu.z), __uint_as_float(oyu.w)};
            const float oxa[4] = {__uint_as_float(oxu.x), __uint_as_float(oxu.y),
                                  __uint_as_float(oxu.z), __uint_as_float(oxu.w)};

#pragma unroll
            for (int j = 0; j < 4; ++j) {
                const float y = (float)(h + ky)     + oya[j];
                const float x = (float)(w + j + kx) + oxa[j];
                const float y0f = floorf(y), x0f = floorf(x);
                const float ly = y - y0f,  lx = x - x0f;
                const int y0 = (int)y0f, x0 = (int)x0f;

                const int cb = ((y0 << 9) + x0) * 4;
                float v00 = bl32(irsrc, cb,              0);
                float v01 = bl32(irsrc, cb + 4,          0);
                float v10 = bl32(irsrc, cb + Wc * 4,     0);
                float v11 = bl32(irsrc, cb + Wc * 4 + 4, 0);
                const bool vx0 = (unsigned)x0       < (unsigned)Wc;
                const bool vx1 = (unsigned)(x0 + 1) < (unsigned)Wc;
                v00 = vx0 ? v00 : 0.f;   v10 = vx0 ? v10 : 0.f;
                v01 = vx1 ? v01 : 0.f;   v11 = vx1 ? v11 : 0.f;

                const float top = v00 + lx * (v01 - v00);
                const float bot = v10 + lx * (v11 - v10);
                acc[j] += wk[k] * (top + ly * (bot - top));
            }
        }
    }

    float4 o;
    o.x = acc[0]; o.y = acc[1]; o.z = acc[2]; o.w = acc[3];
    *reinterpret_cast<float4*>(out + p4) = o;    // 16B aligned, coalesced
}

extern "C" void kernel_launch(void* const* d_in, const int* in_sizes, int n_in,
                              void* d_out, int out_size, void* d_ws, size_t ws_size,
                              hipStream_t stream)
{
    const float* inp = (const float*)d_in[0];   // (8,512,512)
    const float* wgt = (const float*)d_in[1];   // (1,1,3,3) = 9 floats
    const float* off = (const float*)d_in[2];   // (8,18,512,512)
    float* out = (float*)d_out;

    const int nthreads = Bc * HWc / 4;          // 4 px per thread
    const int block = 256;
    const int grid  = nthreads / block;         // 2048

    deform_conv2d_kernel<<<grid, block, 0, stream>>>(inp, wgt, off, out);
}

// Round 9
// 38.119 us; speedup vs baseline: 3.5279x; 3.0945x over previous
//
#include <hip/hip_runtime.h>

constexpr int K  = 3;
constexpr int Hc = 512, Wc = 512, Bc = 8;
constexpr int HWc = Hc * Wc;

typedef __attribute__((ext_vector_type(2))) unsigned int u32x2;
typedef __attribute__((ext_vector_type(4))) unsigned int u32x4;

__device__ __forceinline__ float bl32(__amdgpu_buffer_rsrc_t r, int vo, int so) {
    return __uint_as_float(__builtin_amdgcn_raw_buffer_load_b32(r, vo, so, 0));
}
__device__ __forceinline__ u32x2 bl64(__amdgpu_buffer_rsrc_t r, int vo, int so) {
    return __builtin_amdgcn_raw_buffer_load_b64(r, vo, so, 0);
}
__device__ __forceinline__ u32x4 bl128(__amdgpu_buffer_rsrc_t r, int vo, int so) {
    return __builtin_amdgcn_raw_buffer_load_b128(r, vo, so, 0);
}
__device__ __forceinline__ unsigned umax2(unsigned a, unsigned b) { return a > b ? a : b; }

__global__ __launch_bounds__(256, 6) void deform_conv2d_kernel(
    const float* __restrict__ inp,     // (B,H,W)
    const float* __restrict__ wgt,     // (K*K)
    const float* __restrict__ off,     // (B, 2*K*K, H, W)
    float* __restrict__ out)           // (B,H,W)
{
    const int idx = blockIdx.x * blockDim.x + threadIdx.x;   // 4 pixels per thread
    const int p4  = idx << 2;
    const int b   = p4 >> 18;            // / (512*512)
    const int hw  = p4 & (HWc - 1);
    const int h   = hw >> 9;
    const int w   = hw & (Wc - 1);       // multiple of 4

    __amdgpu_buffer_rsrc_t orsrc = __builtin_amdgcn_make_buffer_rsrc(
        (void*)(off + (size_t)b * (2 * K * K) * HWc), (short)0,
        (2 * K * K) * HWc * 4, 0x00020000);
    __amdgpu_buffer_rsrc_t irsrc = __builtin_amdgcn_make_buffer_rsrc(
        (void*)(inp + (size_t)b * HWc), (short)0, HWc * 4, 0x00020000);

    const int hwB = hw * 4;

    // Issue k=0's offset loads FIRST (their latency hides under the window loads).
    u32x4 oyc = bl128(orsrc, hwB, 0);
    u32x4 oxc = bl128(orsrc, hwB, HWc * 4);

    // ---- shared 4x7 window: rows h-1..h+2, cols w-1..w+5 (zero-padded) ----
    // Row OOB handled free by SRD bounds check (flat index wraps OOB -> 0).
    // Column wrap-aliasing fixed by 3 masks.
    const int  fbB = ((h - 1) * Wc + (w - 1)) * 4;
    const bool m0 = (w >= 1);
    const bool m5 = (w + 4 < Wc);
    const bool m6 = (w + 5 < Wc);

    float win[4][7];
#pragma unroll
    for (int r = 0; r < 4; ++r) {
        const int rb = fbB + r * Wc * 4;
        const float e0 = bl32 (irsrc, rb,      0);   // col w-1
        const u32x4 md = bl128(irsrc, rb + 4,  0);   // cols w..w+3 (16B aligned)
        const u32x2 e5 = bl64 (irsrc, rb + 20, 0);   // cols w+4,w+5 (8B aligned)
        win[r][0] = m0 ? e0 : 0.f;
        win[r][1] = __uint_as_float(md.x);
        win[r][2] = __uint_as_float(md.y);
        win[r][3] = __uint_as_float(md.z);
        win[r][4] = __uint_as_float(md.w);
        win[r][5] = m5 ? __uint_as_float(e5.x) : 0.f;
        win[r][6] = m6 ? __uint_as_float(e5.y) : 0.f;
    }

    float wk[K * K];
#pragma unroll
    for (int k = 0; k < K * K; ++k) wk[k] = wgt[k];   // wave-uniform s_loads

    float acc[4] = {0.f, 0.f, 0.f, 0.f};

    // Per-k structure (the uniform branch doubles as a scheduling fence that
    // stops the compiler from hoisting ALL offset loads -> no spill, cf. R7/R8).
    // Depth-1 software prefetch: issue k+1's loads before k's check consumes k's.
#pragma unroll
    for (int k = 0; k < K * K; ++k) {
        u32x4 oyn, oxn;
        if (k < K * K - 1) {
            oyn = bl128(orsrc, hwB, (2 * (k + 1))     * HWc * 4);
            oxn = bl128(orsrc, hwB, (2 * (k + 1) + 1) * HWc * 4);
        }

        // validity of this k's 8 values: f in [0,1) <=> bits < 0x3F800000u
        // (negatives/NaN/Inf/>=1 all have larger unsigned bit patterns)
        const unsigned vk = umax2(umax2(umax2(oyc.x, oyc.y), umax2(oyc.z, oyc.w)),
                                  umax2(umax2(oxc.x, oxc.y), umax2(oxc.z, oxc.w)));

        const int ky = k / K - 1;
        const int kx = k % K - 1;
        const int r0 = ky + 1;

        if (__all(vk < 0x3F800000u)) {
            // FAST (wave-uniform): floor(y)=h+ky, floor(x)=w+j+kx; ly=oy, lx=ox.
#pragma unroll
            for (int j = 0; j < 4; ++j) {
                const int   c  = j + kx + 1;   // static after unroll
                const float oy = __uint_as_float(j == 0 ? oyc.x : j == 1 ? oyc.y : j == 2 ? oyc.z : oyc.w);
                const float ox = __uint_as_float(j == 0 ? oxc.x : j == 1 ? oxc.y : j == 2 ? oxc.z : oxc.w);
                const float t  = win[r0][c]     + ox * (win[r0][c + 1]     - win[r0][c]);
                const float bo = win[r0 + 1][c] + ox * (win[r0 + 1][c + 1] - win[r0 + 1][c]);
                acc[j] += wk[k] * (t + oy * (bo - t));
            }
        } else {
            // GENERAL (never taken for this data; keeps arbitrary-offset correctness)
#pragma unroll
            for (int j = 0; j < 4; ++j) {
                const float oyv = __uint_as_float(j == 0 ? oyc.x : j == 1 ? oyc.y : j == 2 ? oyc.z : oyc.w);
                const float oxv = __uint_as_float(j == 0 ? oxc.x : j == 1 ? oxc.y : j == 2 ? oxc.z : oxc.w);
                const float y = (float)(h + ky)     + oyv;
                const float x = (float)(w + j + kx) + oxv;
                const float y0f = floorf(y), x0f = floorf(x);
                const float ly = y - y0f,  lx = x - x0f;
                const int y0 = (int)y0f, x0 = (int)x0f;

                const int cb = ((y0 << 9) + x0) * 4;
                float v00 = bl32(irsrc, cb,              0);
                float v01 = bl32(irsrc, cb + 4,          0);
                float v10 = bl32(irsrc, cb + Wc * 4,     0);
                float v11 = bl32(irsrc, cb + Wc * 4 + 4, 0);
                const bool vx0 = (unsigned)x0       < (unsigned)Wc;
                const bool vx1 = (unsigned)(x0 + 1) < (unsigned)Wc;
                v00 = vx0 ? v00 : 0.f;   v10 = vx0 ? v10 : 0.f;
                v01 = vx1 ? v01 : 0.f;   v11 = vx1 ? v11 : 0.f;

                const float top = v00 + lx * (v01 - v00);
                const float bot = v10 + lx * (v11 - v10);
                acc[j] += wk[k] * (top + ly * (bot - top));
            }
        }

        if (k < K * K - 1) { oyc = oyn; oxc = oxn; }
    }

    float4 o;
    o.x = acc[0]; o.y = acc[1]; o.z = acc[2]; o.w = acc[3];
    *reinterpret_cast<float4*>(out + p4) = o;    // 16B aligned, coalesced
}

extern "C" void kernel_launch(void* const* d_in, const int* in_sizes, int n_in,
                              void* d_out, int out_size, void* d_ws, size_t ws_size,
                              hipStream_t stream)
{
    const float* inp = (const float*)d_in[0];   // (8,512,512)
    const float* wgt = (const float*)d_in[1];   // (1,1,3,3) = 9 floats
    const float* off = (const float*)d_in[2];   // (8,18,512,512)
    float* out = (float*)d_out;

    const int nthreads = Bc * HWc / 4;          // 4 px per thread
    const int block = 256;
    const int grid  = nthreads / block;         // 2048

    deform_conv2d_kernel<<<grid, block, 0, stream>>>(inp, wgt, off, out);
}